// Round 3
// baseline (619.556 us; speedup 1.0000x reference)
//
#include <hip/hip_runtime.h>
#include <math.h>

#define NM 50000
#define ND 50000
#define NN 100000   // total nodes
#define DK 256      // feature dim of both sims
#define F  64       // attn feature size
#define SLOPE 0.2f

// proj tiling: 64 rows x 64 cols per block, BK=32, 4x4 micro-tile
#define BR   64
#define BK   32
#define LDP  36     // padded row stride in floats (144B: keeps 16B alignment, spreads banks)
#define NB1  782    // ceil(50000/64)

// ---------------- projection: z = [m_sim @ Wm^T ; d_sim @ Wd^T] ----------------
// 64x64 tile, BK=32. A and W staged in LDS with pad-36 rows (bank-conflict-free
// at the b128 floor). 4x4 register micro-tile, 256 threads = 16tx x 16ty.
// Issue-early staging: next tile's global loads issued before compute.
__global__ __launch_bounds__(256, 4) void proj_kernel(const float* __restrict__ m_sim,
                                                      const float* __restrict__ d_sim,
                                                      const float* __restrict__ Wm,
                                                      const float* __restrict__ Wd,
                                                      float* __restrict__ z) {
    __shared__ float As[BR * LDP];   // 9216 B
    __shared__ float Ws[F * LDP];    // 9216 B

    int bid  = blockIdx.x;
    bool ism = bid < NB1;
    const float* sim = ism ? m_sim : d_sim;
    const float* W   = ism ? Wm : Wd;
    int row0   = (ism ? bid : bid - NB1) * BR;
    int nrows  = ism ? NM : ND;
    int zbase  = ism ? 0 : NM;

    int t  = threadIdx.x;
    int tx = t & 15;
    int ty = t >> 4;

    // staging decomposition: linear float4 index l -> row r = l>>3, quad q = l&7
    int r0 = t >> 3;          // 0..31   (and +32 for second load)
    int q0 = t & 7;           // 0..7

    // clamp source rows (results discarded by store guard)
    int gr0 = row0 + r0;      if (gr0 > nrows - 1) gr0 = nrows - 1;
    int gr1 = row0 + r0 + 32; if (gr1 > nrows - 1) gr1 = nrows - 1;
    const float4* a_src0 = (const float4*)(sim + (size_t)gr0 * DK) + q0;
    const float4* a_src1 = (const float4*)(sim + (size_t)gr1 * DK) + q0;
    const float4* w_src0 = (const float4*)(W + (size_t)r0 * DK) + q0;
    const float4* w_src1 = (const float4*)(W + (size_t)(r0 + 32) * DK) + q0;

    float* a_dst0 = &As[r0 * LDP + q0 * 4];
    float* a_dst1 = &As[(r0 + 32) * LDP + q0 * 4];
    float* w_dst0 = &Ws[r0 * LDP + q0 * 4];
    float* w_dst1 = &Ws[(r0 + 32) * LDP + q0 * 4];

    float acc[4][4];
    #pragma unroll
    for (int i = 0; i < 4; ++i)
        #pragma unroll
        for (int j = 0; j < 4; ++j) acc[i][j] = 0.f;

    // prologue: load k0 = 0
    float4 ra0 = a_src0[0], ra1 = a_src1[0], rw0 = w_src0[0], rw1 = w_src1[0];

    const int NK = DK / BK;   // 8
    for (int step = 0; step < NK; ++step) {
        __syncthreads();
        *(float4*)a_dst0 = ra0;
        *(float4*)a_dst1 = ra1;
        *(float4*)w_dst0 = rw0;
        *(float4*)w_dst1 = rw1;
        __syncthreads();

        if (step + 1 < NK) {   // issue next tile's loads early (overlap with compute)
            int qn = (step + 1) * (BK / 4);
            ra0 = a_src0[qn]; ra1 = a_src1[qn];
            rw0 = w_src0[qn]; rw1 = w_src1[qn];
        }

        #pragma unroll
        for (int k4 = 0; k4 < BK / 4; ++k4) {
            float4 a[4], w[4];
            #pragma unroll
            for (int i = 0; i < 4; ++i)
                a[i] = *(const float4*)&As[(i * 16 + ty) * LDP + k4 * 4];
            #pragma unroll
            for (int j = 0; j < 4; ++j)
                w[j] = *(const float4*)&Ws[(j * 16 + tx) * LDP + k4 * 4];
            #pragma unroll
            for (int i = 0; i < 4; ++i)
                #pragma unroll
                for (int j = 0; j < 4; ++j)
                    acc[i][j] += a[i].x * w[j].x + a[i].y * w[j].y
                               + a[i].z * w[j].z + a[i].w * w[j].w;
        }
    }

    #pragma unroll
    for (int i = 0; i < 4; ++i) {
        int r = row0 + i * 16 + ty;
        if (r < nrows) {
            float* zr = z + (size_t)(zbase + r) * F;
            #pragma unroll
            for (int j = 0; j < 4; ++j) zr[j * 16 + tx] = acc[i][j];
        }
    }
}

// ---------------- degree histogram over dst ----------------
__global__ void hist_kernel(const int* __restrict__ dst, int* __restrict__ deg, int E) {
    int k = blockIdx.x * blockDim.x + threadIdx.x;
    if (k < E) atomicAdd(&deg[dst[k]], 1);
}

// ---------------- block-level inclusive scan (1024 elems / block) ----------------
__global__ __launch_bounds__(256) void scanA(const int* __restrict__ deg,
                                             int* __restrict__ incl,   // = offs+1
                                             int* __restrict__ bsums) {
    __shared__ int sd[256];
    int tid  = threadIdx.x;
    int base = blockIdx.x * 1024 + tid * 4;
    int v[4];
    int run = 0;
    #pragma unroll
    for (int j = 0; j < 4; ++j) {
        int i = base + j;
        int x = (i < NN) ? deg[i] : 0;
        run += x;
        v[j] = run;
    }
    sd[tid] = run;
    __syncthreads();
    for (int off = 1; off < 256; off <<= 1) {
        int t = (tid >= off) ? sd[tid - off] : 0;
        __syncthreads();
        sd[tid] += t;
        __syncthreads();
    }
    int texcl = sd[tid] - run;
    #pragma unroll
    for (int j = 0; j < 4; ++j) {
        int i = base + j;
        if (i < NN) incl[i] = texcl + v[j];
    }
    if (tid == 255) bsums[blockIdx.x] = sd[255];
}

// ---------------- scan of the block sums (exclusive, in place) ----------------
__global__ void scanB(int* __restrict__ bsums, int nb) {
    __shared__ int sd[128];
    int tid = threadIdx.x;
    int x = (tid < nb) ? bsums[tid] : 0;
    sd[tid] = x;
    __syncthreads();
    for (int off = 1; off < 128; off <<= 1) {
        int t = (tid >= off) ? sd[tid - off] : 0;
        __syncthreads();
        sd[tid] += t;
        __syncthreads();
    }
    if (tid < nb) bsums[tid] = sd[tid] - x;
}

// ---------------- finalize offsets + init scatter cursors ----------------
__global__ __launch_bounds__(256) void scanC(int* __restrict__ offs,
                                             int* __restrict__ cursor,
                                             const int* __restrict__ bsums,
                                             const int* __restrict__ deg) {
    int base = blockIdx.x * 1024 + threadIdx.x * 4;
    int add  = bsums[blockIdx.x];
    #pragma unroll
    for (int j = 0; j < 4; ++j) {
        int i = base + j;
        if (i < NN) {
            int v = offs[i + 1] + add;
            offs[i + 1] = v;
            cursor[i]   = v - deg[i];
        }
    }
    if (blockIdx.x == 0 && threadIdx.x == 0) offs[0] = 0;
}

// ---------------- scatter edges into CSR by dst ----------------
__global__ void scatter_kernel(const int* __restrict__ src, const int* __restrict__ dst,
                               int* __restrict__ cursor, int* __restrict__ csr_src, int E) {
    int k = blockIdx.x * blockDim.x + threadIdx.x;
    if (k < E) {
        int d   = dst[k];
        int pos = atomicAdd(&cursor[d], 1);
        csr_src[pos] = src[k];
    }
}

// ---------------- fused per-dst-node: scores + online softmax + aggregation + elu ----------------
// Wave per node. Edges processed in batches of 4: 4 gathers issued back-to-back
// (memory latency /4), 4 independent butterfly reduces interleaved (shfl latency /4),
// then serial-cheap online-softmax updates (rescale skipped when max doesn't grow).
__global__ __launch_bounds__(256) void gat_kernel(const float* __restrict__ z,
                                                  const int* __restrict__ offs,
                                                  const int* __restrict__ csr_src,
                                                  float* __restrict__ out) {
    int tid  = threadIdx.x;
    int node = blockIdx.x * 4 + (tid >> 6);
    int lane = tid & 63;
    int beg = offs[node];
    int end = offs[node + 1];
    float zd = z[(size_t)node * F + lane];
    float m = -INFINITY, ssum = 0.f, h = 0.f;

    for (int j = beg; j < end; j += 4) {
        int   s[4];
        float zs[4], p[4];
        #pragma unroll
        for (int k = 0; k < 4; ++k) {
            int jj = j + k; if (jj > end - 1) jj = end - 1;   // clamp (dup ignored below)
            s[k] = csr_src[jj];
        }
        #pragma unroll
        for (int k = 0; k < 4; ++k) zs[k] = z[(size_t)s[k] * F + lane];
        #pragma unroll
        for (int k = 0; k < 4; ++k) p[k] = zs[k] * zd;
        #pragma unroll
        for (int o = 32; o > 0; o >>= 1) {
            #pragma unroll
            for (int k = 0; k < 4; ++k) p[k] += __shfl_xor(p[k], o, 64);
        }
        int nvalid = end - j; if (nvalid > 4) nvalid = 4;
        #pragma unroll
        for (int k = 0; k < 4; ++k) {
            if (k < nvalid) {
                float e  = (p[k] > 0.f) ? p[k] : SLOPE * p[k];   // leaky_relu
                if (e > m) {                                      // wave-uniform branch
                    float sc = __expf(m - e);                     // exp(-inf)=0 first edge
                    ssum *= sc; h *= sc; m = e;
                }
                float ex = __expf(e - m);
                ssum += ex;
                h    += ex * zs[k];
            }
        }
    }
    float o = (end > beg) ? (h / ssum) : 0.f;
    o = (o > 0.f) ? o : (__expf(o) - 1.f);   // elu (elu(0)=0)
    out[(size_t)node * F + lane] = o;
}

extern "C" void kernel_launch(void* const* d_in, const int* in_sizes, int n_in,
                              void* d_out, int out_size, void* d_ws, size_t ws_size,
                              hipStream_t stream) {
    const float* m_sim = (const float*)d_in[0];
    const float* d_sim = (const float*)d_in[1];
    const float* Wm    = (const float*)d_in[2];
    const float* Wd    = (const float*)d_in[3];
    const int*   src   = (const int*)d_in[4];
    const int*   dst   = (const int*)d_in[5];
    int E = in_sizes[4];
    float* out = (float*)d_out;

    char* ws = (char*)d_ws;
    float* z      = (float*)ws; ws += (size_t)NN * F * 4;
    int*   deg    = (int*)ws;   ws += (size_t)NN * 4;
    int*   offs   = (int*)ws;   ws += (size_t)(NN + 1) * 4;
    int*   cursor = (int*)ws;   ws += (size_t)NN * 4;
    int*   bsums  = (int*)ws;   ws += 128 * 4;
    int*   csr    = (int*)ws;   ws += (size_t)E * 4;

    hipMemsetAsync(deg, 0, (size_t)NN * 4, stream);

    proj_kernel<<<NB1 * 2, 256, 0, stream>>>(m_sim, d_sim, Wm, Wd, z);
    hist_kernel<<<(E + 255) / 256, 256, 0, stream>>>(dst, deg, E);
    int nb = (NN + 1023) / 1024;   // 98
    scanA<<<nb, 256, 0, stream>>>(deg, offs + 1, bsums);
    scanB<<<1, 128, 0, stream>>>(bsums, nb);
    scanC<<<nb, 256, 0, stream>>>(offs, cursor, bsums, deg);
    scatter_kernel<<<(E + 255) / 256, 256, 0, stream>>>(src, dst, cursor, csr, E);
    gat_kernel<<<NN / 4, 256, 0, stream>>>(z, offs, csr, out);
}

// Round 4
// 388.768 us; speedup vs baseline: 1.5936x; 1.5936x over previous
//
#include <hip/hip_runtime.h>
#include <math.h>

#define NM 50000
#define ND 50000
#define NN 100000   // total nodes
#define DK 256      // feature dim of both sims
#define F  64       // attn feature size
#define SLOPE 0.2f

// proj tiling: 64 rows x 64 cols per block, BK=32, 4x4 micro-tile
#define BR   64
#define BK   32
#define LDP  36     // padded row stride in floats (144B: keeps 16B alignment, spreads banks)
#define NB1  782    // ceil(50000/64)

// ---------------- projection: z = [m_sim @ Wm^T ; d_sim @ Wd^T] ----------------
// 64x64 tile, BK=32. A and W staged in LDS with pad-36 rows (verified 0 bank
// conflicts in R3 profile). 4x4 register micro-tile, 256 threads = 16tx x 16ty.
// Issue-early staging: next tile's global loads issued before compute.
// __launch_bounds__(256, 2): R3's (256,4) squeezed to 64 VGPR -> 730 MB of
// scratch spill; natural need is ~95 VGPR -> 4 waves/SIMD, no spill.
__global__ __launch_bounds__(256, 2) void proj_kernel(const float* __restrict__ m_sim,
                                                      const float* __restrict__ d_sim,
                                                      const float* __restrict__ Wm,
                                                      const float* __restrict__ Wd,
                                                      float* __restrict__ z) {
    __shared__ float As[BR * LDP];   // 9216 B
    __shared__ float Ws[F * LDP];    // 9216 B

    int bid  = blockIdx.x;
    bool ism = bid < NB1;
    const float* sim = ism ? m_sim : d_sim;
    const float* W   = ism ? Wm : Wd;
    int row0   = (ism ? bid : bid - NB1) * BR;
    int nrows  = ism ? NM : ND;
    int zbase  = ism ? 0 : NM;

    int t  = threadIdx.x;
    int tx = t & 15;
    int ty = t >> 4;

    // staging decomposition: linear float4 index l -> row r = l>>3, quad q = l&7
    int r0 = t >> 3;          // 0..31   (and +32 for second load)
    int q0 = t & 7;           // 0..7

    // clamp source rows (results discarded by store guard)
    int gr0 = row0 + r0;      if (gr0 > nrows - 1) gr0 = nrows - 1;
    int gr1 = row0 + r0 + 32; if (gr1 > nrows - 1) gr1 = nrows - 1;
    const float4* a_src0 = (const float4*)(sim + (size_t)gr0 * DK) + q0;
    const float4* a_src1 = (const float4*)(sim + (size_t)gr1 * DK) + q0;
    const float4* w_src0 = (const float4*)(W + (size_t)r0 * DK) + q0;
    const float4* w_src1 = (const float4*)(W + (size_t)(r0 + 32) * DK) + q0;

    float* a_dst0 = &As[r0 * LDP + q0 * 4];
    float* a_dst1 = &As[(r0 + 32) * LDP + q0 * 4];
    float* w_dst0 = &Ws[r0 * LDP + q0 * 4];
    float* w_dst1 = &Ws[(r0 + 32) * LDP + q0 * 4];

    float acc[4][4];
    #pragma unroll
    for (int i = 0; i < 4; ++i)
        #pragma unroll
        for (int j = 0; j < 4; ++j) acc[i][j] = 0.f;

    // prologue: load k0 = 0
    float4 ra0 = a_src0[0], ra1 = a_src1[0], rw0 = w_src0[0], rw1 = w_src1[0];

    const int NK = DK / BK;   // 8
    for (int step = 0; step < NK; ++step) {
        __syncthreads();
        *(float4*)a_dst0 = ra0;
        *(float4*)a_dst1 = ra1;
        *(float4*)w_dst0 = rw0;
        *(float4*)w_dst1 = rw1;
        __syncthreads();

        if (step + 1 < NK) {   // issue next tile's loads early (overlap with compute)
            int qn = (step + 1) * (BK / 4);
            ra0 = a_src0[qn]; ra1 = a_src1[qn];
            rw0 = w_src0[qn]; rw1 = w_src1[qn];
        }

        #pragma unroll
        for (int k4 = 0; k4 < BK / 4; ++k4) {
            float4 a[4], w[4];
            #pragma unroll
            for (int i = 0; i < 4; ++i)
                a[i] = *(const float4*)&As[(i * 16 + ty) * LDP + k4 * 4];
            #pragma unroll
            for (int j = 0; j < 4; ++j)
                w[j] = *(const float4*)&Ws[(j * 16 + tx) * LDP + k4 * 4];
            #pragma unroll
            for (int i = 0; i < 4; ++i)
                #pragma unroll
                for (int j = 0; j < 4; ++j)
                    acc[i][j] += a[i].x * w[j].x + a[i].y * w[j].y
                               + a[i].z * w[j].z + a[i].w * w[j].w;
        }
    }

    #pragma unroll
    for (int i = 0; i < 4; ++i) {
        int r = row0 + i * 16 + ty;
        if (r < nrows) {
            float* zr = z + (size_t)(zbase + r) * F;
            #pragma unroll
            for (int j = 0; j < 4; ++j) zr[j * 16 + tx] = acc[i][j];
        }
    }
}

// ---------------- degree histogram over dst ----------------
__global__ void hist_kernel(const int* __restrict__ dst, int* __restrict__ deg, int E) {
    int k = blockIdx.x * blockDim.x + threadIdx.x;
    if (k < E) atomicAdd(&deg[dst[k]], 1);
}

// ---------------- block-level inclusive scan (1024 elems / block) ----------------
__global__ __launch_bounds__(256) void scanA(const int* __restrict__ deg,
                                             int* __restrict__ incl,   // = offs+1
                                             int* __restrict__ bsums) {
    __shared__ int sd[256];
    int tid  = threadIdx.x;
    int base = blockIdx.x * 1024 + tid * 4;
    int v[4];
    int run = 0;
    #pragma unroll
    for (int j = 0; j < 4; ++j) {
        int i = base + j;
        int x = (i < NN) ? deg[i] : 0;
        run += x;
        v[j] = run;
    }
    sd[tid] = run;
    __syncthreads();
    for (int off = 1; off < 256; off <<= 1) {
        int t = (tid >= off) ? sd[tid - off] : 0;
        __syncthreads();
        sd[tid] += t;
        __syncthreads();
    }
    int texcl = sd[tid] - run;
    #pragma unroll
    for (int j = 0; j < 4; ++j) {
        int i = base + j;
        if (i < NN) incl[i] = texcl + v[j];
    }
    if (tid == 255) bsums[blockIdx.x] = sd[255];
}

// ---------------- scan of the block sums (exclusive, in place) ----------------
__global__ void scanB(int* __restrict__ bsums, int nb) {
    __shared__ int sd[128];
    int tid = threadIdx.x;
    int x = (tid < nb) ? bsums[tid] : 0;
    sd[tid] = x;
    __syncthreads();
    for (int off = 1; off < 128; off <<= 1) {
        int t = (tid >= off) ? sd[tid - off] : 0;
        __syncthreads();
        sd[tid] += t;
        __syncthreads();
    }
    if (tid < nb) bsums[tid] = sd[tid] - x;
}

// ---------------- finalize offsets + init scatter cursors ----------------
__global__ __launch_bounds__(256) void scanC(int* __restrict__ offs,
                                             int* __restrict__ cursor,
                                             const int* __restrict__ bsums,
                                             const int* __restrict__ deg) {
    int base = blockIdx.x * 1024 + threadIdx.x * 4;
    int add  = bsums[blockIdx.x];
    #pragma unroll
    for (int j = 0; j < 4; ++j) {
        int i = base + j;
        if (i < NN) {
            int v = offs[i + 1] + add;
            offs[i + 1] = v;
            cursor[i]   = v - deg[i];
        }
    }
    if (blockIdx.x == 0 && threadIdx.x == 0) offs[0] = 0;
}

// ---------------- scatter edges into CSR by dst ----------------
__global__ void scatter_kernel(const int* __restrict__ src, const int* __restrict__ dst,
                               int* __restrict__ cursor, int* __restrict__ csr_src, int E) {
    int k = blockIdx.x * blockDim.x + threadIdx.x;
    if (k < E) {
        int d   = dst[k];
        int pos = atomicAdd(&cursor[d], 1);
        csr_src[pos] = src[k];
    }
}

// ---------------- fused per-dst-node: scores + online softmax + aggregation + elu ----------------
// Wave per node. Edges processed in batches of 4: 4 gathers issued back-to-back
// (memory latency /4), 4 independent butterfly reduces interleaved (shfl latency /4),
// then serial-cheap online-softmax updates (rescale skipped when max doesn't grow).
__global__ __launch_bounds__(256) void gat_kernel(const float* __restrict__ z,
                                                  const int* __restrict__ offs,
                                                  const int* __restrict__ csr_src,
                                                  float* __restrict__ out) {
    int tid  = threadIdx.x;
    int node = blockIdx.x * 4 + (tid >> 6);
    int lane = tid & 63;
    int beg = offs[node];
    int end = offs[node + 1];
    float zd = z[(size_t)node * F + lane];
    float m = -INFINITY, ssum = 0.f, h = 0.f;

    for (int j = beg; j < end; j += 4) {
        int   s[4];
        float zs[4], p[4];
        #pragma unroll
        for (int k = 0; k < 4; ++k) {
            int jj = j + k; if (jj > end - 1) jj = end - 1;   // clamp (dup ignored below)
            s[k] = csr_src[jj];
        }
        #pragma unroll
        for (int k = 0; k < 4; ++k) zs[k] = z[(size_t)s[k] * F + lane];
        #pragma unroll
        for (int k = 0; k < 4; ++k) p[k] = zs[k] * zd;
        #pragma unroll
        for (int o = 32; o > 0; o >>= 1) {
            #pragma unroll
            for (int k = 0; k < 4; ++k) p[k] += __shfl_xor(p[k], o, 64);
        }
        int nvalid = end - j; if (nvalid > 4) nvalid = 4;
        #pragma unroll
        for (int k = 0; k < 4; ++k) {
            if (k < nvalid) {
                float e  = (p[k] > 0.f) ? p[k] : SLOPE * p[k];   // leaky_relu
                if (e > m) {                                      // wave-uniform branch
                    float sc = __expf(m - e);                     // exp(-inf)=0 first edge
                    ssum *= sc; h *= sc; m = e;
                }
                float ex = __expf(e - m);
                ssum += ex;
                h    += ex * zs[k];
            }
        }
    }
    float o = (end > beg) ? (h / ssum) : 0.f;
    o = (o > 0.f) ? o : (__expf(o) - 1.f);   // elu (elu(0)=0)
    out[(size_t)node * F + lane] = o;
}

extern "C" void kernel_launch(void* const* d_in, const int* in_sizes, int n_in,
                              void* d_out, int out_size, void* d_ws, size_t ws_size,
                              hipStream_t stream) {
    const float* m_sim = (const float*)d_in[0];
    const float* d_sim = (const float*)d_in[1];
    const float* Wm    = (const float*)d_in[2];
    const float* Wd    = (const float*)d_in[3];
    const int*   src   = (const int*)d_in[4];
    const int*   dst   = (const int*)d_in[5];
    int E = in_sizes[4];
    float* out = (float*)d_out;

    char* ws = (char*)d_ws;
    float* z      = (float*)ws; ws += (size_t)NN * F * 4;
    int*   deg    = (int*)ws;   ws += (size_t)NN * 4;
    int*   offs   = (int*)ws;   ws += (size_t)(NN + 1) * 4;
    int*   cursor = (int*)ws;   ws += (size_t)NN * 4;
    int*   bsums  = (int*)ws;   ws += 128 * 4;
    int*   csr    = (int*)ws;   ws += (size_t)E * 4;

    hipMemsetAsync(deg, 0, (size_t)NN * 4, stream);

    proj_kernel<<<NB1 * 2, 256, 0, stream>>>(m_sim, d_sim, Wm, Wd, z);
    hist_kernel<<<(E + 255) / 256, 256, 0, stream>>>(dst, deg, E);
    int nb = (NN + 1023) / 1024;   // 98
    scanA<<<nb, 256, 0, stream>>>(deg, offs + 1, bsums);
    scanB<<<1, 128, 0, stream>>>(bsums, nb);
    scanC<<<nb, 256, 0, stream>>>(offs, cursor, bsums, deg);
    scatter_kernel<<<(E + 255) / 256, 256, 0, stream>>>(src, dst, cursor, csr, E);
    gat_kernel<<<NN / 4, 256, 0, stream>>>(z, offs, csr, out);
}